// Round 1
// baseline (721.003 us; speedup 1.0000x reference)
//
#include <hip/hip_runtime.h>

#define DEV __device__ __forceinline__

typedef __bf16 bf16;
typedef bf16 bf16x4 __attribute__((ext_vector_type(4)));
typedef bf16 bf16x8 __attribute__((ext_vector_type(8)));
typedef float f32x4 __attribute__((ext_vector_type(4)));

constexpr int N_NODES = 16384;
constexpr int KN = 25;               // neighbors per node
constexpr int DS = 256, DN = 256, DL = 64;

// ws layout (bytes)
constexpr size_t WS_WLT  = 0;                  // bf16 W_linkT [256][64]   = 32768 B
constexpr size_t WS_WCAT = 32768;              // bf16 WT_cat  [512][256]  = 262144 B
constexpr size_t WS_EXP  = 32768 + 262144;     // bf16 expected [16384][256] = 8 MB

DEV float sigmoid_fast(float x) {
    // 1/(1+2^(-x*log2e)) ; v_exp_f32 + v_rcp_f32, ~1ulp each (threshold is 1e-1)
    return __builtin_amdgcn_rcpf(1.0f + __builtin_amdgcn_exp2f(-1.44269504088896341f * x));
}

// ---------------------------------------------------------------------------
// Kernel 0: convert + transpose weights to bf16 in ws
// ---------------------------------------------------------------------------
__global__ void prep_kernel(const float* __restrict__ W_link,
                            const float* __restrict__ W_self,
                            const float* __restrict__ W_neigh,
                            bf16* __restrict__ wlT, bf16* __restrict__ wcat) {
    int tid = blockIdx.x * blockDim.x + threadIdx.x;
    int stride = gridDim.x * blockDim.x;
    // W_linkT[d][l] = W_link[l][d]
    for (int i = tid; i < DL * DN; i += stride) {
        int d = i >> 6, l = i & 63;
        wlT[i] = (bf16)W_link[l * DN + d];
    }
    // WT_cat[j][k]: j<256 -> W_self[k][j], j>=256 -> W_neigh[k][j-256]
    for (int i = tid; i < 512 * 256; i += stride) {
        int j = i >> 8, kk = i & 255;
        float v = (j < 256) ? W_self[kk * 256 + j] : W_neigh[kk * 256 + (j - 256)];
        wcat[i] = (bf16)v;
    }
}

// ---------------------------------------------------------------------------
// Kernel A: fused gate + link-transform(MFMA) + amplify + weighted mean
// block = 256 threads (4 waves), cooperatively processes NB nodes one at a time
// ---------------------------------------------------------------------------
constexpr int NB = 8;       // nodes per block
constexpr int LPAD = 72;    // LDS row stride (elems); 72*2=144 B keeps 16B align, breaks conflicts

__global__ __launch_bounds__(256, 2)
void fused_agg_kernel(const float* __restrict__ self_vecs,
                      const float* __restrict__ neigh_vecs,
                      const float* __restrict__ link_vecs,
                      const float* __restrict__ probs,
                      const float* __restrict__ g_self_w,
                      const float* __restrict__ g_neigh_w,
                      const float* __restrict__ g_link_w,
                      const bf16* __restrict__ wlT,
                      bf16* __restrict__ exp_out) {
    __shared__ bf16 WT[256 * LPAD];   // W_linkT [d][l], padded
    __shared__ bf16 LK[32 * LPAD];    // link tile [k][l] bf16, rows 25..31 zeroed
    __shared__ float wk_s[32];        // per-neighbor weight (gate/p/25), 0 for pad rows

    const int tid = threadIdx.x;
    const int lane = tid & 63;
    const int w = tid >> 6;        // wave 0..3
    const int c = lane & 15;       // 0..15
    const int q = lane >> 4;       // quad 0..3

    // stage W_linkT -> LDS (coalesced 8B per thread per iter)
    for (int it = 0; it < 16; ++it) {
        int idx = it * 1024 + tid * 4;
        int d = idx >> 6, l = idx & 63;
        *(bf16x4*)&WT[d * LPAD + l] = *(const bf16x4*)&wlT[idx];
    }

    // per-lane gate-weight preloads
    f32x4 gsw = *(const f32x4*)&g_self_w[lane * 4];
    f32x4 glw = *(const f32x4*)&g_link_w[c * 4];
    float gn16[16];
#pragma unroll
    for (int u = 0; u < 4; ++u) {
        f32x4 t = *(const f32x4*)&g_neigh_w[c * 16 + u * 4];
        gn16[u * 4 + 0] = t[0]; gn16[u * 4 + 1] = t[1];
        gn16[u * 4 + 2] = t[2]; gn16[u * 4 + 3] = t[3];
    }

    for (int it = 0; it < NB; ++it) {
        const int n = blockIdx.x * NB + it;
        const float* nbase = neigh_vecs + (size_t)n * KN * DN;

        // ---- trans_self (all waves redundantly; 1KB coalesced) ----
        f32x4 sv = *(const f32x4*)&self_vecs[(size_t)n * DS + lane * 4];
        float ts = sv[0] * gsw[0] + sv[1] * gsw[1] + sv[2] * gsw[2] + sv[3] * gsw[3];
#pragma unroll
        for (int off = 1; off < 64; off <<= 1) ts += __shfl_xor(ts, off);

        // ---- link stage (bf16, MFMA-A layout) + trans_link; wave w owns rows w*8 .. w*8+7 ----
        float tl[2];
#pragma unroll
        for (int i = 0; i < 2; ++i) {
            int row = w * 8 + i * 4 + q;           // 0..31
            bool valid = row < KN;
            f32x4 lv = {0.f, 0.f, 0.f, 0.f};
            if (valid) lv = *(const f32x4*)&link_vecs[((size_t)n * KN + row) * DL + c * 4];
            bf16x4 lb; lb[0] = (bf16)lv[0]; lb[1] = (bf16)lv[1]; lb[2] = (bf16)lv[2]; lb[3] = (bf16)lv[3];
            *(bf16x4*)&LK[row * LPAD + c * 4] = lb;
            float p = lv[0] * glw[0] + lv[1] * glw[1] + lv[2] * glw[2] + lv[3] * glw[3];
            p += __shfl_xor(p, 1); p += __shfl_xor(p, 2);
            p += __shfl_xor(p, 4); p += __shfl_xor(p, 8);
            tl[i] = p;
        }

        // ---- trans_neigh + wk for the same rows ----
#pragma unroll
        for (int i = 0; i < 2; ++i) {
            int row = w * 8 + i * 4 + q;
            bool valid = row < KN;
            float tn = 0.f;
            if (valid) {
                const float* nr = nbase + row * DN + c * 16;
#pragma unroll
                for (int u = 0; u < 4; ++u) {
                    f32x4 nv = *(const f32x4*)&nr[u * 4];
                    tn += nv[0] * gn16[u * 4 + 0] + nv[1] * gn16[u * 4 + 1]
                        + nv[2] * gn16[u * 4 + 2] + nv[3] * gn16[u * 4 + 3];
                }
            }
            tn += __shfl_xor(tn, 1); tn += __shfl_xor(tn, 2);
            tn += __shfl_xor(tn, 4); tn += __shfl_xor(tn, 8);
            float wkv = 0.f;
            if (valid) {
                float pr = probs[n * KN + row];
                wkv = sigmoid_fast(ts + tn + tl[i]) * __builtin_amdgcn_rcpf(pr * 25.0f);
            }
            if (c == 0) wk_s[row] = wkv;
        }

        __syncthreads();   // LK + wk_s ready for all waves (covers WT on iter 0)

        // ---- MFMA trans_links + sigmoid + amplify + reduce over k ----
        float wkA[4], wkB[4];
#pragma unroll
        for (int r = 0; r < 4; ++r) { wkA[r] = wk_s[q * 4 + r]; wkB[r] = wk_s[q * 4 + r + 16]; }
        const int kc = q * 8;
        bf16x8 a00 = *(const bf16x8*)&LK[c * LPAD + kc];
        bf16x8 a01 = *(const bf16x8*)&LK[c * LPAD + kc + 32];
        bf16x8 a10 = *(const bf16x8*)&LK[(c + 16) * LPAD + kc];
        bf16x8 a11 = *(const bf16x8*)&LK[(c + 16) * LPAD + kc + 32];

#pragma unroll
        for (int t = 0; t < 4; ++t) {
            const int d0 = w * 64 + t * 16;
            bf16x8 b0 = *(const bf16x8*)&WT[(d0 + c) * LPAD + kc];
            bf16x8 b1 = *(const bf16x8*)&WT[(d0 + c) * LPAD + kc + 32];
            f32x4 acc0 = {0.f, 0.f, 0.f, 0.f};
            f32x4 acc1 = {0.f, 0.f, 0.f, 0.f};
            acc0 = __builtin_amdgcn_mfma_f32_16x16x32_bf16(a00, b0, acc0, 0, 0, 0);
            acc0 = __builtin_amdgcn_mfma_f32_16x16x32_bf16(a01, b1, acc0, 0, 0, 0);
            acc1 = __builtin_amdgcn_mfma_f32_16x16x32_bf16(a10, b0, acc1, 0, 0, 0);
            acc1 = __builtin_amdgcn_mfma_f32_16x16x32_bf16(a11, b1, acc1, 0, 0, 0);

            const int col = d0 + c;
            const float* np = nbase + col;
            float part = 0.f;
#pragma unroll
            for (int r = 0; r < 4; ++r) {
                int rowA = q * 4 + r;
                int rowB = rowA + 16; if (rowB > 24) rowB = 24;   // wkB==0 there; clamp avoids OOB
                float sA = sigmoid_fast(acc0[r]);
                float sB = sigmoid_fast(acc1[r]);
                part += sA * wkA[r] * np[rowA * DN];
                part += sB * wkB[r] * np[rowB * DN];
            }
            part += __shfl_xor(part, 16);
            part += __shfl_xor(part, 32);
            if (q == 0) exp_out[(size_t)n * DN + col] = (bf16)part;
        }
        __syncthreads();   // protect LK/wk_s restage next node
    }
}

// ---------------------------------------------------------------------------
// Kernel B: out = relu([self | expected] @ blockdiag(W_self, W_neigh))
// 64x64 tile per block, K=256 in 4 steps, bf16 MFMA
// ---------------------------------------------------------------------------
constexpr int BPAD = 72;

__global__ __launch_bounds__(256, 2)
void out_gemm_kernel(const float* __restrict__ self_vecs,
                     const bf16* __restrict__ exp_in,
                     const bf16* __restrict__ wcat,
                     float* __restrict__ out) {
    __shared__ bf16 As[64 * BPAD];
    __shared__ bf16 Bs[64 * BPAD];
    const int tid = threadIdx.x;
    const int lane = tid & 63;
    const int w = tid >> 6;
    const int c = lane & 15, q = lane >> 4;
    const int wm = w >> 1, wn = w & 1;
    const int m0 = blockIdx.x * 64;
    const int j0 = blockIdx.y * 64;
    const bool use_exp = j0 >= 256;

    f32x4 acc[2][2];
#pragma unroll
    for (int i = 0; i < 2; ++i)
#pragma unroll
        for (int j = 0; j < 2; ++j) acc[i][j] = (f32x4){0.f, 0.f, 0.f, 0.f};

    const int srow = tid >> 4;          // 0..15
    const int scol = (tid & 15) * 4;    // 0..60

    for (int ks = 0; ks < 4; ++ks) {
        const int k0 = ks * 64;
        __syncthreads();
#pragma unroll
        for (int i = 0; i < 4; ++i) {
            int row = srow + i * 16;
            if (use_exp) {
                *(bf16x4*)&As[row * BPAD + scol] =
                    *(const bf16x4*)&exp_in[(size_t)(m0 + row) * 256 + k0 + scol];
            } else {
                f32x4 v = *(const f32x4*)&self_vecs[(size_t)(m0 + row) * 256 + k0 + scol];
                bf16x4 b; b[0] = (bf16)v[0]; b[1] = (bf16)v[1]; b[2] = (bf16)v[2]; b[3] = (bf16)v[3];
                *(bf16x4*)&As[row * BPAD + scol] = b;
            }
            *(bf16x4*)&Bs[row * BPAD + scol] =
                *(const bf16x4*)&wcat[(size_t)(j0 + row) * 256 + k0 + scol];
        }
        __syncthreads();
        const int kc = q * 8;
#pragma unroll
        for (int i = 0; i < 2; ++i) {
            bf16x8 a0 = *(const bf16x8*)&As[(wm * 32 + i * 16 + c) * BPAD + kc];
            bf16x8 a1 = *(const bf16x8*)&As[(wm * 32 + i * 16 + c) * BPAD + kc + 32];
#pragma unroll
            for (int j = 0; j < 2; ++j) {
                bf16x8 b0 = *(const bf16x8*)&Bs[(wn * 32 + j * 16 + c) * BPAD + kc];
                bf16x8 b1 = *(const bf16x8*)&Bs[(wn * 32 + j * 16 + c) * BPAD + kc + 32];
                acc[i][j] = __builtin_amdgcn_mfma_f32_16x16x32_bf16(a0, b0, acc[i][j], 0, 0, 0);
                acc[i][j] = __builtin_amdgcn_mfma_f32_16x16x32_bf16(a1, b1, acc[i][j], 0, 0, 0);
            }
        }
    }

#pragma unroll
    for (int i = 0; i < 2; ++i)
#pragma unroll
        for (int j = 0; j < 2; ++j)
#pragma unroll
            for (int r = 0; r < 4; ++r) {
                int row = m0 + wm * 32 + i * 16 + q * 4 + r;
                int col = j0 + wn * 32 + j * 16 + c;
                float v = acc[i][j][r];
                out[(size_t)row * 512 + col] = v > 0.f ? v : 0.f;
            }
}

// ---------------------------------------------------------------------------
extern "C" void kernel_launch(void* const* d_in, const int* in_sizes, int n_in,
                              void* d_out, int out_size, void* d_ws, size_t ws_size,
                              hipStream_t stream) {
    const float* self_vecs  = (const float*)d_in[0];
    const float* neigh_vecs = (const float*)d_in[1];
    const float* link_vecs  = (const float*)d_in[2];
    const float* probs      = (const float*)d_in[3];
    const float* g_self_w   = (const float*)d_in[4];
    const float* g_neigh_w  = (const float*)d_in[5];
    const float* g_link_w   = (const float*)d_in[6];
    const float* W_link     = (const float*)d_in[7];
    const float* W_self     = (const float*)d_in[8];
    const float* W_neigh    = (const float*)d_in[9];
    float* out = (float*)d_out;

    char* ws = (char*)d_ws;
    bf16* wlT  = (bf16*)(ws + WS_WLT);
    bf16* wcat = (bf16*)(ws + WS_WCAT);
    bf16* expb = (bf16*)(ws + WS_EXP);

    prep_kernel<<<dim3(128), dim3(256), 0, stream>>>(W_link, W_self, W_neigh, wlT, wcat);
    fused_agg_kernel<<<dim3(N_NODES / NB), dim3(256), 0, stream>>>(
        self_vecs, neigh_vecs, link_vecs, probs, g_self_w, g_neigh_w, g_link_w, wlT, expb);
    out_gemm_kernel<<<dim3(256, 8), dim3(256), 0, stream>>>(self_vecs, expb, wcat, out);
}

// Round 2
// 669.656 us; speedup vs baseline: 1.0767x; 1.0767x over previous
//
#include <hip/hip_runtime.h>

#define DEV __device__ __forceinline__

typedef __bf16 bf16;
typedef bf16 bf16x4 __attribute__((ext_vector_type(4)));
typedef bf16 bf16x8 __attribute__((ext_vector_type(8)));
typedef float f32x4 __attribute__((ext_vector_type(4)));

constexpr int N_NODES = 16384;
constexpr int KN = 25;               // neighbors per node
constexpr int DS = 256, DN = 256, DL = 64;

// ws layout (bytes)
constexpr size_t WS_WLT  = 0;                  // bf16 W_linkT [256][64]   = 32768 B
constexpr size_t WS_WCAT = 32768;              // bf16 WT_cat  [512][256]  = 262144 B
constexpr size_t WS_EXP  = 32768 + 262144;     // bf16 expected [16384][256] = 8 MB

DEV float sigmoid_fast(float x) {
    return __builtin_amdgcn_rcpf(1.0f + __builtin_amdgcn_exp2f(-1.44269504088896341f * x));
}

DEV float dot4(f32x4 a, f32x4 b) {
    return a[0] * b[0] + a[1] * b[1] + a[2] * b[2] + a[3] * b[3];
}

// ---------------------------------------------------------------------------
// Kernel 0: convert + transpose weights to bf16 in ws
// ---------------------------------------------------------------------------
__global__ void prep_kernel(const float* __restrict__ W_link,
                            const float* __restrict__ W_self,
                            const float* __restrict__ W_neigh,
                            bf16* __restrict__ wlT, bf16* __restrict__ wcat) {
    int tid = blockIdx.x * blockDim.x + threadIdx.x;
    int stride = gridDim.x * blockDim.x;
    for (int i = tid; i < DL * DN; i += stride) {
        int d = i >> 6, l = i & 63;
        wlT[i] = (bf16)W_link[l * DN + d];         // W_linkT[d][l]
    }
    for (int i = tid; i < 512 * 256; i += stride) {
        int j = i >> 8, kk = i & 255;
        float v = (j < 256) ? W_self[kk * 256 + j] : W_neigh[kk * 256 + (j - 256)];
        wcat[i] = (bf16)v;
    }
}

// ---------------------------------------------------------------------------
// Kernel A: per-WAVE fused gate + link-MFMA + amplify + weighted mean.
// No barriers in the node loop; each neigh row read exactly once.
// ---------------------------------------------------------------------------
constexpr int NPW = 8;     // nodes per wave; grid = 16384/(4*NPW) = 512 blocks
constexpr int WTS = 72;    // WT row stride (elems): 144 B, breaks b128 conflicts
constexpr int STS = 264;   // ST row stride (elems): 528 B

__global__ __launch_bounds__(256, 2)
void fused_agg_kernel(const float* __restrict__ self_vecs,
                      const float* __restrict__ neigh_vecs,
                      const float* __restrict__ link_vecs,
                      const float* __restrict__ probs,
                      const float* __restrict__ g_self_w,
                      const float* __restrict__ g_neigh_w,
                      const float* __restrict__ g_link_w,
                      const bf16* __restrict__ wlT,
                      bf16* __restrict__ exp_out) {
    __shared__ bf16 WT[256 * WTS];        // 36 KB, shared: W_linkT [d][l]
    __shared__ bf16 ST[4][16 * STS];      // 33 KB: per-wave sigmoid(trans_links) 16 rows

    const int tid = threadIdx.x;
    const int lane = tid & 63;
    const int w = tid >> 6;
    const int c = lane & 15;
    const int q = lane >> 4;

    // stage W_linkT -> LDS once
    for (int i = 0; i < 16; ++i) {
        int idx = i * 1024 + tid * 4;
        int d = idx >> 6, l = idx & 63;
        *(bf16x4*)&WT[d * WTS + l] = *(const bf16x4*)&wlT[idx];
    }
    __syncthreads();

    // per-lane weight preloads
    f32x4 gsw = *(const f32x4*)&g_self_w[lane * 4];
    f32x4 gnw = *(const f32x4*)&g_neigh_w[lane * 4];
    f32x4 glw0a = *(const f32x4*)&g_link_w[q * 8];
    f32x4 glw0b = *(const f32x4*)&g_link_w[q * 8 + 4];
    f32x4 glw1a = *(const f32x4*)&g_link_w[32 + q * 8];
    f32x4 glw1b = *(const f32x4*)&g_link_w[32 + q * 8 + 4];

    for (int it = 0; it < NPW; ++it) {
        const int n = (blockIdx.x * 4 + w) * NPW + it;
        const float* nbase = neigh_vecs + (size_t)n * KN * DN;
        const float* lbase = link_vecs + (size_t)n * KN * DL;

        // ---- trans_self (full-wave dot) ----
        f32x4 sv = *(const f32x4*)&self_vecs[(size_t)n * DS + lane * 4];
        float ts = dot4(sv, gsw);
#pragma unroll
        for (int off = 1; off < 64; off <<= 1) ts += __shfl_xor(ts, off);

        // ---- link fragments (MFMA-A layout, straight from global) + trans_link ----
        // frag A: rows 0..15 (row = c); frag B: rows 16..31 (row = c+16, pad>=25 zero)
        f32x4 v0 = *(const f32x4*)&lbase[c * DL + q * 8];
        f32x4 v1 = *(const f32x4*)&lbase[c * DL + q * 8 + 4];
        f32x4 v2 = *(const f32x4*)&lbase[c * DL + 32 + q * 8];
        f32x4 v3 = *(const f32x4*)&lbase[c * DL + 32 + q * 8 + 4];
        const int rB = c + 16;
        const f32x4 z = {0.f, 0.f, 0.f, 0.f};
        f32x4 u0 = z, u1 = z, u2 = z, u3 = z;
        if (rB < KN) {
            u0 = *(const f32x4*)&lbase[rB * DL + q * 8];
            u1 = *(const f32x4*)&lbase[rB * DL + q * 8 + 4];
            u2 = *(const f32x4*)&lbase[rB * DL + 32 + q * 8];
            u3 = *(const f32x4*)&lbase[rB * DL + 32 + q * 8 + 4];
        }
        bf16x8 a00, a01, a10, a11;
#pragma unroll
        for (int j = 0; j < 4; ++j) {
            a00[j] = (bf16)v0[j]; a00[j + 4] = (bf16)v1[j];
            a01[j] = (bf16)v2[j]; a01[j + 4] = (bf16)v3[j];
            a10[j] = (bf16)u0[j]; a10[j + 4] = (bf16)u1[j];
            a11[j] = (bf16)u2[j]; a11[j + 4] = (bf16)u3[j];
        }
        float tlA = dot4(v0, glw0a) + dot4(v1, glw0b) + dot4(v2, glw1a) + dot4(v3, glw1b);
        tlA += __shfl_xor(tlA, 16); tlA += __shfl_xor(tlA, 32);
        float tlB = dot4(u0, glw0a) + dot4(u1, glw0b) + dot4(u2, glw1a) + dot4(u3, glw1b);
        tlB += __shfl_xor(tlB, 16); tlB += __shfl_xor(tlB, 32);

        // lane k (k=0..24) holds gate partial ts+tl[k] and 1/(p[k]*25)
        float gk = ts + ((lane & 63) < 16 ? tlA : tlB);
        float pv = (lane < KN) ? probs[n * KN + lane] : 1.0f;
        float wden = __builtin_amdgcn_rcpf(pv * 25.0f);

        f32x4 accd = z;    // expected accumulator: cols lane*4..+3

#pragma unroll
        for (int half = 0; half < 2; ++half) {
            const bf16x8 aF0 = half ? a10 : a00;
            const bf16x8 aF1 = half ? a11 : a01;
            // MFMA 16 rows x 256 cols, sigmoid, stash bf16 to per-wave LDS
#pragma unroll
            for (int t = 0; t < 16; ++t) {
                bf16x8 b0 = *(const bf16x8*)&WT[(t * 16 + c) * WTS + q * 8];
                bf16x8 b1 = *(const bf16x8*)&WT[(t * 16 + c) * WTS + 32 + q * 8];
                f32x4 acc = z;
                acc = __builtin_amdgcn_mfma_f32_16x16x32_bf16(aF0, b0, acc, 0, 0, 0);
                acc = __builtin_amdgcn_mfma_f32_16x16x32_bf16(aF1, b1, acc, 0, 0, 0);
#pragma unroll
                for (int r = 0; r < 4; ++r)
                    ST[w][(q * 4 + r) * STS + t * 16 + c] = (bf16)sigmoid_fast(acc[r]);
            }
            // single pass over this half's neigh rows (each row loaded ONCE)
            const int k0 = half * 16;
            const int k1 = half ? KN : 16;
#pragma unroll
            for (int k = k0; k < k1; ++k) {
                f32x4 nv = *(const f32x4*)&nbase[(size_t)k * DN + lane * 4];
                bf16x4 s4 = *(const bf16x4*)&ST[w][(k - k0) * STS + lane * 4];
                float tn = dot4(nv, gnw);
#pragma unroll
                for (int off = 1; off < 64; off <<= 1) tn += __shfl_xor(tn, off);
                float wkk = sigmoid_fast(tn + __shfl(gk, k)) * __shfl(wden, k);
#pragma unroll
                for (int j = 0; j < 4; ++j)
                    accd[j] += nv[j] * (float)s4[j] * wkk;
            }
        }

        bf16x4 eo;
#pragma unroll
        for (int j = 0; j < 4; ++j) eo[j] = (bf16)accd[j];
        *(bf16x4*)&exp_out[(size_t)n * DN + lane * 4] = eo;
    }
}

// ---------------------------------------------------------------------------
// Kernel B: out = relu([self | expected] @ blockdiag(W_self, W_neigh))
// ---------------------------------------------------------------------------
constexpr int BPAD = 72;

__global__ __launch_bounds__(256, 2)
void out_gemm_kernel(const float* __restrict__ self_vecs,
                     const bf16* __restrict__ exp_in,
                     const bf16* __restrict__ wcat,
                     float* __restrict__ out) {
    __shared__ bf16 As[64 * BPAD];
    __shared__ bf16 Bs[64 * BPAD];
    const int tid = threadIdx.x;
    const int lane = tid & 63;
    const int w = tid >> 6;
    const int c = lane & 15, q = lane >> 4;
    const int wm = w >> 1, wn = w & 1;
    const int m0 = blockIdx.x * 64;
    const int j0 = blockIdx.y * 64;
    const bool use_exp = j0 >= 256;

    f32x4 acc[2][2];
#pragma unroll
    for (int i = 0; i < 2; ++i)
#pragma unroll
        for (int j = 0; j < 2; ++j) acc[i][j] = (f32x4){0.f, 0.f, 0.f, 0.f};

    const int srow = tid >> 4;
    const int scol = (tid & 15) * 4;

    for (int ks = 0; ks < 4; ++ks) {
        const int k0 = ks * 64;
        __syncthreads();
#pragma unroll
        for (int i = 0; i < 4; ++i) {
            int row = srow + i * 16;
            if (use_exp) {
                *(bf16x4*)&As[row * BPAD + scol] =
                    *(const bf16x4*)&exp_in[(size_t)(m0 + row) * 256 + k0 + scol];
            } else {
                f32x4 v = *(const f32x4*)&self_vecs[(size_t)(m0 + row) * 256 + k0 + scol];
                bf16x4 b; b[0] = (bf16)v[0]; b[1] = (bf16)v[1]; b[2] = (bf16)v[2]; b[3] = (bf16)v[3];
                *(bf16x4*)&As[row * BPAD + scol] = b;
            }
            *(bf16x4*)&Bs[row * BPAD + scol] =
                *(const bf16x4*)&wcat[(size_t)(j0 + row) * 256 + k0 + scol];
        }
        __syncthreads();
        const int kc = q * 8;
#pragma unroll
        for (int i = 0; i < 2; ++i) {
            bf16x8 a0 = *(const bf16x8*)&As[(wm * 32 + i * 16 + c) * BPAD + kc];
            bf16x8 a1 = *(const bf16x8*)&As[(wm * 32 + i * 16 + c) * BPAD + kc + 32];
#pragma unroll
            for (int j = 0; j < 2; ++j) {
                bf16x8 b0 = *(const bf16x8*)&Bs[(wn * 32 + j * 16 + c) * BPAD + kc];
                bf16x8 b1 = *(const bf16x8*)&Bs[(wn * 32 + j * 16 + c) * BPAD + kc + 32];
                acc[i][j] = __builtin_amdgcn_mfma_f32_16x16x32_bf16(a0, b0, acc[i][j], 0, 0, 0);
                acc[i][j] = __builtin_amdgcn_mfma_f32_16x16x32_bf16(a1, b1, acc[i][j], 0, 0, 0);
            }
        }
    }

#pragma unroll
    for (int i = 0; i < 2; ++i)
#pragma unroll
        for (int j = 0; j < 2; ++j)
#pragma unroll
            for (int r = 0; r < 4; ++r) {
                int row = m0 + wm * 32 + i * 16 + q * 4 + r;
                int col = j0 + wn * 32 + j * 16 + c;
                float v = acc[i][j][r];
                out[(size_t)row * 512 + col] = v > 0.f ? v : 0.f;
            }
}

// ---------------------------------------------------------------------------
extern "C" void kernel_launch(void* const* d_in, const int* in_sizes, int n_in,
                              void* d_out, int out_size, void* d_ws, size_t ws_size,
                              hipStream_t stream) {
    const float* self_vecs  = (const float*)d_in[0];
    const float* neigh_vecs = (const float*)d_in[1];
    const float* link_vecs  = (const float*)d_in[2];
    const float* probs      = (const float*)d_in[3];
    const float* g_self_w   = (const float*)d_in[4];
    const float* g_neigh_w  = (const float*)d_in[5];
    const float* g_link_w   = (const float*)d_in[6];
    const float* W_link     = (const float*)d_in[7];
    const float* W_self     = (const float*)d_in[8];
    const float* W_neigh    = (const float*)d_in[9];
    float* out = (float*)d_out;

    char* ws = (char*)d_ws;
    bf16* wlT  = (bf16*)(ws + WS_WLT);
    bf16* wcat = (bf16*)(ws + WS_WCAT);
    bf16* expb = (bf16*)(ws + WS_EXP);

    prep_kernel<<<dim3(128), dim3(256), 0, stream>>>(W_link, W_self, W_neigh, wlT, wcat);
    fused_agg_kernel<<<dim3(N_NODES / (4 * NPW)), dim3(256), 0, stream>>>(
        self_vecs, neigh_vecs, link_vecs, probs, g_self_w, g_neigh_w, g_link_w, wlT, expb);
    out_gemm_kernel<<<dim3(256, 8), dim3(256), 0, stream>>>(self_vecs, expb, wcat, out);
}